// Round 8
// baseline (226.494 us; speedup 1.0000x reference)
//
#include <hip/hip_runtime.h>

// Problem constants (fixed by the reference):
//   B=64, L=2048, D=1024, seq f32, begin/end int32 (harness downcasts int64),
//   out f32 [B, D]
#define B_ 64
#define L_ 2048
#define D_ 1024
#define SPLIT 64   // slices per batch -> grid (64,64) = 4096 blocks
// Grid (SPLIT, B_): linear id = s + 64*b -> each CU serves ~16 distinct
// batches (de-aliased, round-6 fix) + 2x oversubscription for dynamic
// balancing. Quantum <= 16 rows.
//
// Fused last-block-done reduction: batch b's reduce starts the moment its
// 64 slices are done (overlaps remaining stage-1 work) instead of waiting
// for a global kernel boundary. Counters live in ws after the partials.

#define WS_PARTIALS_F4 ((size_t)B_ * SPLIT * (D_ / 4))   // 16 MB of float4s

__global__ __launch_bounds__(64) void zero_cnt_kernel(unsigned int* __restrict__ cnt) {
    cnt[threadIdx.x] = 0u;   // 64 counters, one block
}

__global__ __launch_bounds__(256) void seg_mean_fused(
    const float* __restrict__ seq,
    const int* __restrict__ begin,
    const int* __restrict__ end,
    float* __restrict__ ws,
    unsigned int* __restrict__ cnt,
    float* __restrict__ out)
{
    const int s  = blockIdx.x;
    const int b  = blockIdx.y;
    const int bg = begin[b];
    const int en = end[b];
    const int len = en - bg;             // >= 1

    const int per = (len + SPLIT - 1) / SPLIT;
    const int l0  = bg + s * per;
    const int l1  = min(l0 + per, en);   // may be empty -> stores zeros

    const int col = threadIdx.x;         // one float4 of the D=1024 row
    const float4* __restrict__ base =
        reinterpret_cast<const float4*>(seq + (size_t)b * L_ * D_);

    float4 a0 = make_float4(0.f, 0.f, 0.f, 0.f);
    float4 a1 = a0, a2 = a0, a3 = a0;

    int l = l0;
    for (; l + 4 <= l1; l += 4) {        // 4 independent 16B loads in flight
        float4 v0 = base[(size_t)(l + 0) * (D_ / 4) + col];
        float4 v1 = base[(size_t)(l + 1) * (D_ / 4) + col];
        float4 v2 = base[(size_t)(l + 2) * (D_ / 4) + col];
        float4 v3 = base[(size_t)(l + 3) * (D_ / 4) + col];
        a0.x += v0.x; a0.y += v0.y; a0.z += v0.z; a0.w += v0.w;
        a1.x += v1.x; a1.y += v1.y; a1.z += v1.z; a1.w += v1.w;
        a2.x += v2.x; a2.y += v2.y; a2.z += v2.z; a2.w += v2.w;
        a3.x += v3.x; a3.y += v3.y; a3.z += v3.z; a3.w += v3.w;
    }
    for (; l < l1; ++l) {
        float4 v = base[(size_t)l * (D_ / 4) + col];
        a0.x += v.x; a0.y += v.y; a0.z += v.z; a0.w += v.w;
    }

    const float inv = 1.0f / (float)len; // pre-scale so the reduce is a plain sum
    float4 t;
    t.x = (a0.x + a1.x + a2.x + a3.x) * inv;
    t.y = (a0.y + a1.y + a2.y + a3.y) * inv;
    t.z = (a0.z + a1.z + a2.z + a3.z) * inv;
    t.w = (a0.w + a1.w + a2.w + a3.w) * inv;

    float4* __restrict__ w4 = reinterpret_cast<float4*>(ws);
    w4[((size_t)(b * SPLIT + s)) * (D_ / 4) + col] = t;   // unconditional

    // ---- completion signal (rocPRIM-style last-block-done) ----
    __syncthreads();                 // drains this block's stores (vmcnt(0) before barrier)
    __shared__ unsigned int s_old;
    if (threadIdx.x == 0) {
        __threadfence();             // release: make ws writes device-visible
        s_old = atomicAdd(&cnt[b], 1u);
    }
    __syncthreads();

    if (s_old == SPLIT - 1) {        // this block is last for batch b: reduce now
        __threadfence();             // acquire: see all other blocks' ws writes
        const float4* __restrict__ w4r =
            reinterpret_cast<const float4*>(ws) + (size_t)b * SPLIT * (D_ / 4);
        float4 acc = make_float4(0.f, 0.f, 0.f, 0.f);
        #pragma unroll 8
        for (int s2 = 0; s2 < SPLIT; ++s2) {
            float4 v = w4r[(size_t)s2 * (D_ / 4) + col];
            acc.x += v.x; acc.y += v.y; acc.z += v.z; acc.w += v.w;
        }
        reinterpret_cast<float4*>(out)[(size_t)b * (D_ / 4) + col] = acc;
    }
}

extern "C" void kernel_launch(void* const* d_in, const int* in_sizes, int n_in,
                              void* d_out, int out_size, void* d_ws, size_t ws_size,
                              hipStream_t stream) {
    const float* seq   = (const float*)d_in[0];
    const int*   begin = (const int*)d_in[1];   // int32: harness downcasts jnp.int64
    const int*   end   = (const int*)d_in[2];
    float*       out   = (float*)d_out;
    float*       ws    = (float*)d_ws;          // partials: 16 MB, then counters
    unsigned int* cnt  = (unsigned int*)(ws + WS_PARTIALS_F4 * 4);

    zero_cnt_kernel<<<1, 64, 0, stream>>>(cnt);  // counters must be 0 each call

    dim3 g(SPLIT, B_);                           // s fastest -> de-alias batch->CU
    seg_mean_fused<<<g, 256, 0, stream>>>(seq, begin, end, ws, cnt, out);
}

// Round 9
// 34.962 us; speedup vs baseline: 6.4782x; 6.4782x over previous
//
#include <hip/hip_runtime.h>

// Problem constants (fixed by the reference):
//   B=64, L=2048, D=1024, seq f32, begin/end int32 (harness downcasts int64),
//   out f32 [B, D]
#define B_ 64
#define L_ 2048
#define D_ 1024
#define SPLIT 64   // slices per batch -> stage1 grid (64,64) = 4096 blocks
// Stage1 grid (SPLIT, B_): linear id = s + 64*b -> each CU serves ~16 distinct
// batches (de-aliased; round-6 fix) + 2x oversubscription for dynamic
// balancing. Quantum <= 16 rows. NO fences/atomics — round 8 showed per-block
// device-scope __threadfence costs ~80ns serialized at TCC (330us total).

// Stage 1: block (s,b) accumulates rows [bg+s*per, min(bg+(s+1)*per,en)) of
// batch b, stores pre-scaled partial (zeros if empty) to ws[b][s][:].
__global__ __launch_bounds__(256) void seg_mean_stage1(
    const float* __restrict__ seq,
    const int* __restrict__ begin,
    const int* __restrict__ end,
    float* __restrict__ ws)
{
    const int s  = blockIdx.x;
    const int b  = blockIdx.y;
    const int bg = begin[b];
    const int en = end[b];
    const int len = en - bg;             // >= 1

    const int per = (len + SPLIT - 1) / SPLIT;
    const int l0  = bg + s * per;
    const int l1  = min(l0 + per, en);   // may be empty -> stores zeros

    const int col = threadIdx.x;         // one float4 of the D=1024 row
    const float4* __restrict__ base =
        reinterpret_cast<const float4*>(seq + (size_t)b * L_ * D_);

    float4 a0 = make_float4(0.f, 0.f, 0.f, 0.f);
    float4 a1 = a0, a2 = a0, a3 = a0;

    int l = l0;
    for (; l + 4 <= l1; l += 4) {        // 4 independent 16B loads in flight
        float4 v0 = base[(size_t)(l + 0) * (D_ / 4) + col];
        float4 v1 = base[(size_t)(l + 1) * (D_ / 4) + col];
        float4 v2 = base[(size_t)(l + 2) * (D_ / 4) + col];
        float4 v3 = base[(size_t)(l + 3) * (D_ / 4) + col];
        a0.x += v0.x; a0.y += v0.y; a0.z += v0.z; a0.w += v0.w;
        a1.x += v1.x; a1.y += v1.y; a1.z += v1.z; a1.w += v1.w;
        a2.x += v2.x; a2.y += v2.y; a2.z += v2.z; a2.w += v2.w;
        a3.x += v3.x; a3.y += v3.y; a3.z += v3.z; a3.w += v3.w;
    }
    for (; l < l1; ++l) {
        float4 v = base[(size_t)l * (D_ / 4) + col];
        a0.x += v.x; a0.y += v.y; a0.z += v.z; a0.w += v.w;
    }

    const float inv = 1.0f / (float)len; // pre-scale so stage2 is a plain sum
    float4 t;
    t.x = (a0.x + a1.x + a2.x + a3.x) * inv;
    t.y = (a0.y + a1.y + a2.y + a3.y) * inv;
    t.z = (a0.z + a1.z + a2.z + a3.z) * inv;
    t.w = (a0.w + a1.w + a2.w + a3.w) * inv;

    float4* __restrict__ w4 = reinterpret_cast<float4*>(ws);
    w4[((size_t)(b * SPLIT + s)) * (D_ / 4) + col] = t;   // unconditional
}

// Stage 2: grid (B_, 4), 256 blocks -> full-chip BW for the 16 MB ws read.
// Block (b,q) covers float4 cols [q*64,(q+1)*64); 256 threads = 64 cols x
// 4 s-groups. Sums ALL 64 slots (no begin/end dependency, no divergence),
// then LDS-reduces the 4 s-groups and writes out.
__global__ __launch_bounds__(256) void seg_mean_stage2(
    const float* __restrict__ ws,
    float* __restrict__ out)
{
    const int b    = blockIdx.x;
    const int q    = blockIdx.y;
    const int lane = threadIdx.x & 63;   // col within quarter
    const int sg   = threadIdx.x >> 6;   // s-group 0..3
    const int col4 = q * 64 + lane;      // float4 col 0..255

    const float4* __restrict__ w4 =
        reinterpret_cast<const float4*>(ws) + (size_t)b * SPLIT * (D_ / 4);

    float4 acc = make_float4(0.f, 0.f, 0.f, 0.f);
    #pragma unroll
    for (int s = sg; s < SPLIT; s += 4) {   // 16 iters, coalesced 1KB/wave
        float4 v = w4[(size_t)s * (D_ / 4) + col4];
        acc.x += v.x; acc.y += v.y; acc.z += v.z; acc.w += v.w;
    }

    __shared__ float4 red[256];
    red[threadIdx.x] = acc;
    __syncthreads();

    if (sg == 0) {
        float4 r0 = red[lane];
        float4 r1 = red[lane + 64];
        float4 r2 = red[lane + 128];
        float4 r3 = red[lane + 192];
        float4 t;
        t.x = (r0.x + r1.x) + (r2.x + r3.x);
        t.y = (r0.y + r1.y) + (r2.y + r3.y);
        t.z = (r0.z + r1.z) + (r2.z + r3.z);
        t.w = (r0.w + r1.w) + (r2.w + r3.w);
        reinterpret_cast<float4*>(out)[(size_t)b * (D_ / 4) + col4] = t;
    }
}

extern "C" void kernel_launch(void* const* d_in, const int* in_sizes, int n_in,
                              void* d_out, int out_size, void* d_ws, size_t ws_size,
                              hipStream_t stream) {
    const float* seq   = (const float*)d_in[0];
    const int*   begin = (const int*)d_in[1];   // int32: harness downcasts jnp.int64
    const int*   end   = (const int*)d_in[2];
    float*       out   = (float*)d_out;
    float*       ws    = (float*)d_ws;          // needs 64*64*1024*4 = 16 MB

    dim3 g1(SPLIT, B_);                         // s fastest -> de-alias batch->CU
    seg_mean_stage1<<<g1, 256, 0, stream>>>(seq, begin, end, ws);
    dim3 g2(B_, 4);
    seg_mean_stage2<<<g2, 256, 0, stream>>>(ws, out);
}